// Round 3
// baseline (30091.071 us; speedup 1.0000x reference)
//
#include <hip/hip_runtime.h>
#include <math.h>
#include <stddef.h>

#define BB 256
#define TT 512
#define IND 256
#define HH 1024
#define OUTD 256

typedef __attribute__((ext_vector_type(8))) short short8;
typedef __attribute__((ext_vector_type(4))) float f32x4;

#define MFMA __builtin_amdgcn_mfma_f32_16x16x32_bf16

// ---- fp32 -> 3-term bf16 split (v ~= hi+mid+lo, rel err ~2^-26) ------------
__device__ __forceinline__ unsigned short bf16_rne(float f) {
  unsigned u = __builtin_bit_cast(unsigned, f);
  u += 0x7FFFu + ((u >> 16) & 1u);
  return (unsigned short)(u >> 16);
}
__device__ __forceinline__ float bf16_f(unsigned short h) {
  unsigned u = ((unsigned)h) << 16;
  return __builtin_bit_cast(float, u);
}
__device__ __forceinline__ void split3(float v, unsigned short& hi,
                                       unsigned short& mi, unsigned short& lo) {
  hi = bf16_rne(v);
  float r = v - bf16_f(hi);      // exact (Dekker-style split)
  mi = bf16_rne(r);
  float r2 = r - bf16_f(mi);     // exact
  lo = bf16_rne(r2);
}

// ---- prep: split a fp32 array into 3 bf16 planes ---------------------------
__global__ __launch_bounds__(256) void split_w(
    const float* __restrict__ src, int n, unsigned short* __restrict__ hi,
    unsigned short* __restrict__ mi, unsigned short* __restrict__ lo)
{
  int i = blockIdx.x * 256 + threadIdx.x;
  if (i >= n) return;
  unsigned short a, b, c;
  split3(src[i], a, b, c);
  hi[i] = a; mi[i] = b; lo[i] = c;
}

// ---- init: h0 = 0 (fp32 plane + 3 bf16 term planes) ------------------------
__global__ __launch_bounds__(256) void init_h(
    float* __restrict__ hf, unsigned short* __restrict__ ht)
{
  const int i = blockIdx.x * 256 + threadIdx.x;       // 262144 total
  hf[i] = 0.f;
  ht[i] = 0; ht[i + BB * HH] = 0; ht[i + 2 * BB * HH] = 0;
}

// ---------------------------------------------------------------------------
// gru_step: one fused recurrent step.
// grid 256 blocks (XCD-swizzled -> (bt,jt)), 256 thr = 4 waves.
// Wave w: rows [b0+16w,+16), cols [j0,+16) x 3 gates. No LDS, no barriers.
// S = [x_t | h] * [Wx | Wh]^T via 16x16x32 bf16 MFMA, 3-term split (6 MFMA per
// fp32 product, terms down to 2^-18). n-gate x/h parts kept in separate accs.
// Epilogue: gates + h update + re-split of h_next.
// A-frag: lane l holds A[l&15][8*(l>>4)..+7]; B-frag: lane l holds
// W[j0+(l&15)][8*(l>>4)..+7]; C: col=lane&15, row=(lane>>4)*4+reg (m89).
// ---------------------------------------------------------------------------
__global__ __launch_bounds__(256, 1) void gru_step(
    const float* __restrict__ x,
    const unsigned short* __restrict__ Wxs,   // [3][3072][256]
    const unsigned short* __restrict__ Whs,   // [3][3072][1024]
    const float* __restrict__ bx, const float* __restrict__ bh,
    const float* __restrict__ hprev_f,        // [256][1024]
    const unsigned short* __restrict__ hprev_t, // [3][256][1024]
    float* __restrict__ hnext_f,
    unsigned short* __restrict__ hnext_t,
    int t)
{
  // XCD-aware remap: 8 XCDs, each gets a contiguous jt-octet (W-slice ~3MB L2-res)
  const int id  = blockIdx.x;           // 0..255
  const int xcd = id & 7;
  const int sub = id >> 3;              // 0..31
  const int jt  = xcd * 8 + (sub & 7);  // 0..63
  const int bt  = sub >> 3;             // 0..3

  const int lane = threadIdx.x & 63;
  const int wv   = threadIdx.x >> 6;    // wave = m-frag
  const int lrow = lane & 15;
  const int lko  = lane >> 4;           // k-octet 0..3
  const int b0 = bt * 64;
  const int j0 = jt * 16;
  const int arow = b0 + wv * 16 + lrow;

  f32x4 acc0[4] = {{0,0,0,0},{0,0,0,0},{0,0,0,0},{0,0,0,0}}; // r,z,nx,nh
  f32x4 acc1[4] = {{0,0,0,0},{0,0,0,0},{0,0,0,0},{0,0,0,0}};

  const size_t hplane = (size_t)BB * HH;

#define SIXMFMA(GI)                                                            \
  acc0[GI] = MFMA(a_hi, b_hi, acc0[GI], 0, 0, 0);                              \
  acc1[GI] = MFMA(a_hi, b_mi, acc1[GI], 0, 0, 0);                              \
  acc0[GI] = MFMA(a_mi, b_hi, acc0[GI], 0, 0, 0);                              \
  acc1[GI] = MFMA(a_hi, b_lo, acc1[GI], 0, 0, 0);                              \
  acc0[GI] = MFMA(a_mi, b_mi, acc0[GI], 0, 0, 0);                              \
  acc1[GI] = MFMA(a_lo, b_hi, acc1[GI], 0, 0, 0);

  // ---- x part: K = 256, convert fp32 -> 3-term on the fly ----
  {
    const float* xbase = x + ((size_t)arow * TT + t) * IND;
    #pragma unroll 2
    for (int kc = 0; kc < 8; ++kc) {
      const int k = kc * 32 + lko * 8;
      float xv[8];
      *reinterpret_cast<float4*>(&xv[0]) =
          *reinterpret_cast<const float4*>(&xbase[k]);
      *reinterpret_cast<float4*>(&xv[4]) =
          *reinterpret_cast<const float4*>(&xbase[k + 4]);
      short8 a_hi, a_mi, a_lo;
      #pragma unroll
      for (int e = 0; e < 8; ++e) {
        unsigned short h_, m_, l_;
        split3(xv[e], h_, m_, l_);
        a_hi[e] = (short)h_; a_mi[e] = (short)m_; a_lo[e] = (short)l_;
      }
      #pragma unroll
      for (int g = 0; g < 3; ++g) {
        const unsigned short* wp =
            Wxs + (size_t)(g * HH + j0 + lrow) * IND + k;
        const short8 b_hi = *reinterpret_cast<const short8*>(wp);
        const short8 b_mi = *reinterpret_cast<const short8*>(wp + (size_t)3072 * IND);
        const short8 b_lo = *reinterpret_cast<const short8*>(wp + (size_t)2 * 3072 * IND);
        if (g == 0)      { SIXMFMA(0) }
        else if (g == 1) { SIXMFMA(1) }
        else             { SIXMFMA(2) }   // n-gate x-part
      }
    }
  }

  // ---- h part: K = 1024, pre-split planes ----
  {
    const unsigned short* hb = hprev_t + (size_t)arow * HH;
    #pragma unroll 4
    for (int kc = 0; kc < 32; ++kc) {
      const int k = kc * 32 + lko * 8;
      const short8 a_hi = *reinterpret_cast<const short8*>(hb + k);
      const short8 a_mi = *reinterpret_cast<const short8*>(hb + hplane + k);
      const short8 a_lo = *reinterpret_cast<const short8*>(hb + 2 * hplane + k);
      #pragma unroll
      for (int g = 0; g < 3; ++g) {
        const unsigned short* wp =
            Whs + (size_t)(g * HH + j0 + lrow) * HH + k;
        const short8 b_hi = *reinterpret_cast<const short8*>(wp);
        const short8 b_mi = *reinterpret_cast<const short8*>(wp + (size_t)3072 * HH);
        const short8 b_lo = *reinterpret_cast<const short8*>(wp + (size_t)2 * 3072 * HH);
        if (g == 0)      { SIXMFMA(0) }
        else if (g == 1) { SIXMFMA(1) }
        else             { SIXMFMA(3) }   // n-gate h-part
      }
    }
  }

  // ---- fused gate epilogue ----
  const int j = j0 + lrow;
  const float bxr = bx[j],          bhr = bh[j];
  const float bxz = bx[HH + j],     bhz = bh[HH + j];
  const float bxn = bx[2 * HH + j], bhn = bh[2 * HH + j];
  #pragma unroll
  for (int i = 0; i < 4; ++i) {
    const int row = b0 + wv * 16 + lko * 4 + i;   // C row = (lane>>4)*4+reg
    const float sr = acc0[0][i] + acc1[0][i] + bxr + bhr;
    const float sz = acc0[1][i] + acc1[1][i] + bxz + bhz;
    const float xn = acc0[2][i] + acc1[2][i] + bxn;
    const float hn = acc0[3][i] + acc1[3][i] + bhn;
    const float r  = 1.f / (1.f + __expf(-sr));
    const float z  = 1.f / (1.f + __expf(-sz));
    const float n  = tanhf(xn + r * hn);
    const float hp = hprev_f[(size_t)row * HH + j];
    const float hv = (1.f - z) * hp + z * n;      // nonstandard update (per ref)
    hnext_f[(size_t)row * HH + j] = hv;
    unsigned short th, tm, tl;
    split3(hv, th, tm, tl);
    hnext_t[(size_t)row * HH + j] = th;
    hnext_t[hplane + (size_t)row * HH + j] = tm;
    hnext_t[2 * hplane + (size_t)row * HH + j] = tl;
  }
}

// ---------------------------------------------------------------------------
// final_gemm: out[b,o] = h[b,:] . Wf[o,:] + bf[o]   (256x256x1024, runs once)
// ---------------------------------------------------------------------------
__global__ __launch_bounds__(256) void final_gemm(
    const float* __restrict__ h, const float* __restrict__ Wf,
    const float* __restrict__ bf, float* __restrict__ out)
{
  __shared__ float As[32][36];
  __shared__ float Ws[32][36];
  const int tid = threadIdx.x;
  const int b0 = blockIdx.x * 32, o0 = blockIdx.y * 32;
  const int to = tid & 31, tb = tid >> 5;
  float acc[4] = {};
  for (int kc = 0; kc < HH; kc += 32) {
    __syncthreads();
    #pragma unroll
    for (int p = 0; p < 4; ++p) {
      const int f = tid + 256 * p;
      const int row = f >> 5, c = f & 31;
      As[c][row] = h[(size_t)(b0 + row) * HH + kc + c];
      Ws[c][row] = Wf[(size_t)(o0 + row) * HH + kc + c];
    }
    __syncthreads();
    #pragma unroll
    for (int c = 0; c < 32; ++c) {
      const float4 a = *reinterpret_cast<const float4*>(&As[c][tb * 4]);
      const float w = Ws[c][to];
      acc[0] += a.x * w; acc[1] += a.y * w; acc[2] += a.z * w; acc[3] += a.w * w;
    }
  }
  #pragma unroll
  for (int i = 0; i < 4; ++i)
    out[(size_t)(b0 + tb * 4 + i) * OUTD + o0 + to] = acc[i] + bf[o0 + to];
}

// ---------------------------------------------------------------------------
extern "C" void kernel_launch(void* const* d_in, const int* in_sizes, int n_in,
                              void* d_out, int out_size, void* d_ws, size_t ws_size,
                              hipStream_t stream)
{
  const float* x  = (const float*)d_in[0];
  const float* Wx = (const float*)d_in[1];
  const float* bx = (const float*)d_in[2];
  const float* Wh = (const float*)d_in[3];
  const float* bh = (const float*)d_in[4];
  const float* Wf = (const float*)d_in[5];
  const float* bf = (const float*)d_in[6];
  float* out = (float*)d_out;

  // workspace layout (28.8 MB total):
  //   hf0, hf1          : 2 x 256x1024 fp32
  //   Whs [3][3072][1024] bf16-bits, Wxs [3][3072][256], ht0/ht1 [3][256][1024]
  float* wsf = (float*)d_ws;
  float* hf0 = wsf;
  float* hf1 = wsf + (size_t)BB * HH;
  unsigned short* u = (unsigned short*)(wsf + 2 * (size_t)BB * HH);
  unsigned short* Whs = u;                                   // 9,437,184
  unsigned short* Wxs = Whs + (size_t)3 * 3072 * HH;         // 2,359,296
  unsigned short* ht0 = Wxs + (size_t)3 * 3072 * IND;        //   786,432
  unsigned short* ht1 = ht0 + (size_t)3 * BB * HH;

  const int nWh = 3 * HH * HH;    // 3,145,728
  const int nWx = 3 * HH * IND;   //   786,432
  split_w<<<dim3((nWh + 255) / 256), 256, 0, stream>>>(
      Wh, nWh, Whs, Whs + (size_t)3072 * HH, Whs + (size_t)2 * 3072 * HH);
  split_w<<<dim3((nWx + 255) / 256), 256, 0, stream>>>(
      Wx, nWx, Wxs, Wxs + (size_t)3072 * IND, Wxs + (size_t)2 * 3072 * IND);
  init_h<<<dim3(1024), 256, 0, stream>>>(hf0, ht0);

  float* cf = hf0; float* nf = hf1;
  unsigned short* ct = ht0; unsigned short* nt_ = ht1;
  for (int t = 0; t < TT; ++t) {
    gru_step<<<dim3(256), 256, 0, stream>>>(x, Wxs, Whs, bx, bh,
                                            cf, ct, nf, nt_, t);
    float* tf = cf; cf = nf; nf = tf;
    unsigned short* tt = ct; ct = nt_; nt_ = tt;
  }
  final_gemm<<<dim3(8, 8), 256, 0, stream>>>(cf, Wf, bf, out);
}

// Round 4
// 26309.283 us; speedup vs baseline: 1.1437x; 1.1437x over previous
//
#include <hip/hip_runtime.h>
#include <math.h>
#include <stddef.h>

#define BB 256
#define TT 512
#define IND 256
#define HH 1024
#define KV 1280                  // virtual K = 256 (x) + 1024 (h)
#define NCH 40                   // K-chunks of 32
#define XCH 8                    // chunks 0..7 are x-part

typedef __attribute__((ext_vector_type(8))) short short8;
typedef __attribute__((ext_vector_type(4))) float f32x4;
#define MFMA __builtin_amdgcn_mfma_f32_16x16x32_bf16

typedef __attribute__((address_space(1))) const unsigned char gconst_b;
typedef __attribute__((address_space(3))) unsigned char lds_b;

// ---- fp32 -> 3-term bf16 split (v ~= hi+mid+lo, rel err ~2^-26) ------------
__device__ __forceinline__ unsigned short bf16_rne(float f) {
  unsigned u = __builtin_bit_cast(unsigned, f);
  u += 0x7FFFu + ((u >> 16) & 1u);
  return (unsigned short)(u >> 16);
}
__device__ __forceinline__ float bf16_f(unsigned short h) {
  unsigned u = ((unsigned)h) << 16;
  return __builtin_bit_cast(float, u);
}
__device__ __forceinline__ void split3(float v, unsigned short& hi,
                                       unsigned short& mi, unsigned short& lo) {
  hi = bf16_rne(v);
  float r = v - bf16_f(hi);
  mi = bf16_rne(r);
  float r2 = r - bf16_f(mi);
  lo = bf16_rne(r2);
}

// ---- prep: Wcat[p][col][kv]  kv<256 -> Wx[col][kv], else Wh[col][kv-256] ---
__global__ __launch_bounds__(256) void split_wcat(
    const float* __restrict__ Wx, const float* __restrict__ Wh,
    unsigned short* __restrict__ Wc)
{
  const int col = blockIdx.y;                     // 0..3071
  const int kv  = blockIdx.x * 256 + threadIdx.x; // 0..1279
  const float v = (kv < IND) ? Wx[(size_t)col * IND + kv]
                             : Wh[(size_t)col * HH + (kv - IND)];
  unsigned short a, b, c;
  split3(v, a, b, c);
  const size_t o = (size_t)col * KV + kv;
  const size_t ps = (size_t)3072 * KV;
  Wc[o] = a; Wc[o + ps] = b; Wc[o + 2 * ps] = c;
}

// ---- init: h0 = 0 (fp32 plane + 3 bf16 planes) -----------------------------
__global__ __launch_bounds__(256) void init_h(
    float* __restrict__ hf, unsigned short* __restrict__ ht)
{
  const int i = blockIdx.x * 256 + threadIdx.x;   // 262144 total
  hf[i] = 0.f;
  ht[i] = 0; ht[i + BB * HH] = 0; ht[i + 2 * BB * HH] = 0;
}

// ---------------------------------------------------------------------------
// gru_step: one fused recurrent step.
// 256 blocks = 4 m-tiles (64 rows) x 64 jj-tiles (16 h-cols x 3 gates = 48 N)
// 4 waves; wave = 16 rows x 48 cols (3 gate-frags of 16x16).
// B (Wcat split planes) dbuf-staged in LDS via global_load_lds (9KB/chunk):
//   layout [plane][gate][slot=k-octet][col16] -> 1KB-aligned, conflict-free.
// A (x split on the fly / h pre-split planes) direct global->reg, prefetch+1.
// Epilogue: gates + h update + re-split (no second kernel, no partials).
// ---------------------------------------------------------------------------
__global__ __launch_bounds__(256, 1) void gru_step(
    const float* __restrict__ x,
    const unsigned short* __restrict__ Wc,     // [3][3072][1280]
    const float* __restrict__ bx, const float* __restrict__ bh,
    const float* __restrict__ hf,              // [256][1024] fp32
    const unsigned short* __restrict__ ht,     // [3][256][1024]
    float* __restrict__ hnf,
    unsigned short* __restrict__ hnt,
    int t)
{
  __shared__ unsigned short Bs[2 * 4608];      // 2 x 9KB

  const int id  = blockIdx.x;
  const int xcd = id & 7;
  const int sub = id >> 3;
  const int jt  = xcd * 8 + (sub & 7);         // 0..63  (h-col tile)
  const int mt  = sub >> 3;                    // 0..3   (row tile)

  const int tid  = threadIdx.x;
  const int lane = tid & 63;
  const int wv   = tid >> 6;
  const int l15  = lane & 15;
  const int lko  = lane >> 4;                  // k-octet 0..3
  const int r0   = mt * 64 + wv * 16;
  const int jj0  = jt * 16;

  const size_t wps = (size_t)3072 * KV;        // W plane stride
  const size_t hps = (size_t)BB * HH;          // h plane stride

  f32x4 aR0 = {0,0,0,0}, aR1 = {0,0,0,0};
  f32x4 aZ0 = {0,0,0,0}, aZ1 = {0,0,0,0};
  f32x4 aNx0 = {0,0,0,0}, aNx1 = {0,0,0,0};
  f32x4 aNh0 = {0,0,0,0}, aNh1 = {0,0,0,0};

  // stage one K-chunk of B into LDS buffer `buf` (waves 0..2, plane = wv)
  // instr (p,g): lane l -> col16 = l&15, slot = l>>4
  //   src = Wc_p[(g*1024 + jj0 + (l&15)) * 1280 + kc*32 + (l>>4)*8]
  //   dst = Bs[buf*4608 + (p*3+g)*512 + lane*8]
#define STAGE(KC, BUF)                                                         \
  if (wv < 3) {                                                                \
    const unsigned short* wp_ = Wc + (size_t)wv * wps;                         \
    _Pragma("unroll")                                                          \
    for (int g = 0; g < 3; ++g) {                                              \
      const unsigned short* src_ =                                             \
          wp_ + (size_t)(g * HH + jj0 + l15) * KV + (KC) * 32 + lko * 8;       \
      __builtin_amdgcn_global_load_lds(                                        \
          (const gconst_b*)src_,                                               \
          (lds_b*)&Bs[(BUF) * 4608 + (wv * 3 + g) * 512], 16, 0, 0);           \
    }                                                                          \
  }

  // A-frag loaders (3 planes, 16B each)
  short8 cah, cam, cal;            // current
  short8 nah, nam, nal;            // next

#define LOADA_H(KC, AH, AM, AL)                                                \
  {                                                                            \
    const unsigned short* hb_ =                                                \
        ht + (size_t)(r0 + l15) * HH + ((KC) - XCH) * 32 + lko * 8;            \
    AH = *reinterpret_cast<const short8*>(hb_);                                \
    AM = *reinterpret_cast<const short8*>(hb_ + hps);                          \
    AL = *reinterpret_cast<const short8*>(hb_ + 2 * hps);                      \
  }

#define LOADA_X(KC, AH, AM, AL)                                                \
  {                                                                            \
    const float* xb_ = x + ((size_t)(r0 + l15) * TT + t) * IND + (KC) * 32     \
                         + lko * 8;                                            \
    float xv_[8];                                                              \
    *reinterpret_cast<float4*>(&xv_[0]) =                                      \
        *reinterpret_cast<const float4*>(xb_);                                 \
    *reinterpret_cast<float4*>(&xv_[4]) =                                      \
        *reinterpret_cast<const float4*>(xb_ + 4);                             \
    _Pragma("unroll")                                                          \
    for (int e_ = 0; e_ < 8; ++e_) {                                           \
      unsigned short h_, m_, l_;                                               \
      split3(xv_[e_], h_, m_, l_);                                             \
      AH[e_] = (short)h_; AM[e_] = (short)m_; AL[e_] = (short)l_;              \
    }                                                                          \
  }

  STAGE(0, 0)
  LOADA_X(0, cah, cam, cal)

  for (int kc = 0; kc < NCH; ++kc) {
    __syncthreads();               // stage(kc) landed; prev reads done
    const int nk = kc + 1;
    if (nk < NCH) {
      STAGE(nk, nk & 1)
      if (nk < XCH) { LOADA_X(nk, nah, nam, nal) }
      else          { LOADA_H(nk, nah, nam, nal) }
    }

    const int bb = (kc & 1) * 4608;
    const int fo = lko * 128 + l15 * 8;
    #pragma unroll
    for (int g = 0; g < 3; ++g) {
      const short8 bh_ = *reinterpret_cast<const short8*>(&Bs[bb + g * 512 + fo]);
      const short8 bm_ = *reinterpret_cast<const short8*>(&Bs[bb + (3 + g) * 512 + fo]);
      const short8 bl_ = *reinterpret_cast<const short8*>(&Bs[bb + (6 + g) * 512 + fo]);
      f32x4 *p0, *p1;
      if (g == 0)      { p0 = &aR0;  p1 = &aR1; }
      else if (g == 1) { p0 = &aZ0;  p1 = &aZ1; }
      else if (kc < XCH) { p0 = &aNx0; p1 = &aNx1; }
      else             { p0 = &aNh0; p1 = &aNh1; }
      *p0 = MFMA(cah, bh_, *p0, 0, 0, 0);
      *p1 = MFMA(cah, bm_, *p1, 0, 0, 0);
      *p0 = MFMA(cam, bh_, *p0, 0, 0, 0);
      *p1 = MFMA(cah, bl_, *p1, 0, 0, 0);
      *p0 = MFMA(cam, bm_, *p0, 0, 0, 0);
      *p1 = MFMA(cal, bh_, *p1, 0, 0, 0);
    }
    cah = nah; cam = nam; cal = nal;
  }

  // ---- fused gate epilogue (C: col = lane&15, row = (lane>>4)*4 + reg) ----
  const int jj = jj0 + l15;
  const float bxr = bx[jj],          bhr = bh[jj];
  const float bxz = bx[HH + jj],     bhz = bh[HH + jj];
  const float bxn = bx[2 * HH + jj], bhn = bh[2 * HH + jj];
  #pragma unroll
  for (int i = 0; i < 4; ++i) {
    const int row = r0 + lko * 4 + i;
    const float sr = aR0[i] + aR1[i] + bxr + bhr;
    const float sz = aZ0[i] + aZ1[i] + bxz + bhz;
    const float xn = aNx0[i] + aNx1[i] + bxn;
    const float hn = aNh0[i] + aNh1[i] + bhn;
    const float r  = 1.f / (1.f + __expf(-sr));
    const float z  = 1.f / (1.f + __expf(-sz));
    const float n  = tanhf(xn + r * hn);
    const float hp = hf[(size_t)row * HH + jj];
    const float hv = (1.f - z) * hp + z * n;    // nonstandard update (per ref)
    hnf[(size_t)row * HH + jj] = hv;
    unsigned short th, tm, tl;
    split3(hv, th, tm, tl);
    hnt[(size_t)row * HH + jj] = th;
    hnt[hps + (size_t)row * HH + jj] = tm;
    hnt[2 * hps + (size_t)row * HH + jj] = tl;
  }
#undef STAGE
#undef LOADA_H
#undef LOADA_X
}

// ---------------------------------------------------------------------------
// final_gemm: out[b,o] = h[b,:] . Wf[o,:] + bf[o]   (256x256x1024, runs once)
// ---------------------------------------------------------------------------
__global__ __launch_bounds__(256) void final_gemm(
    const float* __restrict__ h, const float* __restrict__ Wf,
    const float* __restrict__ bf, float* __restrict__ out)
{
  __shared__ float As[32][36];
  __shared__ float Ws[32][36];
  const int tid = threadIdx.x;
  const int b0 = blockIdx.x * 32, o0 = blockIdx.y * 32;
  const int to = tid & 31, tb = tid >> 5;
  float acc[4] = {};
  for (int kc = 0; kc < HH; kc += 32) {
    __syncthreads();
    #pragma unroll
    for (int p = 0; p < 4; ++p) {
      const int f = tid + 256 * p;
      const int row = f >> 5, c = f & 31;
      As[c][row] = h[(size_t)(b0 + row) * HH + kc + c];
      Ws[c][row] = Wf[(size_t)(o0 + row) * HH + kc + c];
    }
    __syncthreads();
    #pragma unroll
    for (int c = 0; c < 32; ++c) {
      const float4 a = *reinterpret_cast<const float4*>(&As[c][tb * 4]);
      const float w = Ws[c][to];
      acc[0] += a.x * w; acc[1] += a.y * w; acc[2] += a.z * w; acc[3] += a.w * w;
    }
  }
  #pragma unroll
  for (int i = 0; i < 4; ++i)
    out[(size_t)(b0 + tb * 4 + i) * 256 + o0 + to] = acc[i] + bf[o0 + to];
}

// ---------------------------------------------------------------------------
extern "C" void kernel_launch(void* const* d_in, const int* in_sizes, int n_in,
                              void* d_out, int out_size, void* d_ws, size_t ws_size,
                              hipStream_t stream)
{
  const float* x  = (const float*)d_in[0];
  const float* Wx = (const float*)d_in[1];
  const float* bx = (const float*)d_in[2];
  const float* Wh = (const float*)d_in[3];
  const float* bh = (const float*)d_in[4];
  const float* Wf = (const float*)d_in[5];
  const float* bf = (const float*)d_in[6];
  float* out = (float*)d_out;

  // ws layout (28.7 MB):
  //   hf0, hf1                 : 2 x 262144 f32
  //   Wc  [3][3072][1280] bf16 : 11,796,480 ush
  //   ht0, ht1 [3][256][1024]  : 2 x 786,432 ush
  float* wsf = (float*)d_ws;
  float* hf0 = wsf;
  float* hf1 = wsf + (size_t)BB * HH;
  unsigned short* Wc  = (unsigned short*)(wsf + 2 * (size_t)BB * HH);
  unsigned short* ht0 = Wc + (size_t)3 * 3072 * KV;
  unsigned short* ht1 = ht0 + (size_t)3 * BB * HH;

  split_wcat<<<dim3(5, 3072), 256, 0, stream>>>(Wx, Wh, Wc);
  init_h<<<dim3(1024), 256, 0, stream>>>(hf0, ht0);

  float* cf = hf0; float* nf = hf1;
  unsigned short* ct = ht0; unsigned short* nt_ = ht1;
  for (int t = 0; t < TT; ++t) {
    gru_step<<<dim3(256), 256, 0, stream>>>(x, Wc, bx, bh, cf, ct, nf, nt_, t);
    float* tf = cf; cf = nf; nf = tf;
    unsigned short* tt = ct; ct = nt_; nt_ = tt;
  }
  final_gemm<<<dim3(8, 8), 256, 0, stream>>>(cf, Wf, bf, out);
}